// Round 5
// baseline (785.720 us; speedup 1.0000x reference)
//
#include <hip/hip_runtime.h>
#include <hip/hip_fp16.h>
#include <cstddef>
#include <cstdint>

// HyenaCascade: depthwise causal conv (K=3) -> 8-pole diagonal SSM scan
// (exact replacement for the reference's FFT long-conv) -> gated output.
//
// v6: single fused kernel (545 MB traffic vs v4's 702 MB). v5's
// cg::this_grid().sync() was non-deterministically broken under the
// harness's graph capture (cooperative metadata lost). Replaced with a
// hand-rolled device-scope atomic barrier: counter in workspace (zeroed
// via hipMemsetAsync each call), release fetch_add + acquire spin-load
// (forces L2 writeback / cache invalidate around the A exchange), s_sleep
// backoff + safety valve. Normal launch; 512 blocks = exactly 2/CU
// co-resident (launch_bounds(256,2) caps VGPR at 256; x1v lives in 128
// persistent __half2 regs, all statically indexed via full unroll).
namespace {
constexpr int kB    = 2;
constexpr int kL    = 8192;
constexpr int kHid  = 2048;   // HIDDEN == GROUPS
constexpr int kC3   = 6144;   // 3*HIDDEN
constexpr int kS    = 8;      // state size
constexpr int kNC   = 32;     // sequence chunks
constexpr int kCL   = kL / kNC;    // 256 rows per chunk
constexpr int kPair = kCL / 2;     // 128 row-pairs (one __half2 each)
constexpr unsigned kNBlk = kB * kNC * 8;  // 512 blocks
} // namespace

__global__ __launch_bounds__(256, 2) void hyena_fused(
    const float* __restrict__ u, const float* __restrict__ w,
    const float* __restrict__ bias, const float* __restrict__ lp,
    const float* __restrict__ res, const float* __restrict__ Dv,
    float* __restrict__ A, unsigned* __restrict__ cnt,
    float* __restrict__ out)
{
  const int tid   = threadIdx.x;
  const int slice = blockIdx.x & 7;          // 8 slices of 256 channels
  const int ch    = (blockIdx.x >> 3) & 31;  // chunk 0..31
  const int b     = blockIdx.x >> 8;         // batch
  const int d     = slice * 256 + tid;       // channel, wave = 64 consecutive
  const int head  = d >> 7;
  const int c2    = head * 384 + (d & 127);  // x2 column in u
  const int c1    = c2 + 128;                // x1 column
  const int cv    = c2 + 256;                // v column

  const float w10 = w[c1*3+0], w11 = w[c1*3+1], w12 = w[c1*3+2], b1 = bias[c1];
  const float wv0 = w[cv*3+0], wv1 = w[cv*3+1], wv2 = w[cv*3+2], bv = bias[cv];

  float p[kS], s[kS];
  #pragma unroll
  for (int j = 0; j < kS; ++j) { p[j] = expf(lp[d*kS + j]); s[j] = 0.f; }

  const int l0 = ch * kCL;
  const float* ub = u + (size_t)b * kL * kC3;
  const float* up = ub + (size_t)l0 * kC3;

  // conv history (rows l0-2, l0-1); zero-pad at sequence start
  float m2 = 0.f, m1 = 0.f, n2 = 0.f, n1 = 0.f;
  if (l0 >= 2) { m2 = ub[(size_t)(l0-2)*kC3 + c1]; n2 = ub[(size_t)(l0-2)*kC3 + cv]; }
  if (l0 >= 1) { m1 = ub[(size_t)(l0-1)*kC3 + c1]; n1 = ub[(size_t)(l0-1)*kC3 + cv]; }

  // ---- phase A: x1v into 128 persistent half2 regs + local scan ----------
  __half2 xv[kPair];
  #pragma unroll
  for (int k = 0; k < kPair; ++k) {
    const float a0 = up[(size_t)(2*k  )*kC3 + c1];
    const float e0 = up[(size_t)(2*k  )*kC3 + cv];
    const float a1 = up[(size_t)(2*k+1)*kC3 + c1];
    const float e1 = up[(size_t)(2*k+1)*kC3 + cv];
    const float x1a = fmaf(w10, m2, fmaf(w11, m1, fmaf(w12, a0, b1)));
    const float vva = fmaf(wv0, n2, fmaf(wv1, n1, fmaf(wv2, e0, bv)));
    const float x0  = x1a * vva;
    #pragma unroll
    for (int j = 0; j < kS; ++j) s[j] = fmaf(p[j], s[j], x0);
    const float x1b = fmaf(w10, m1, fmaf(w11, a0, fmaf(w12, a1, b1)));
    const float vvb = fmaf(wv0, n1, fmaf(wv1, e0, fmaf(wv2, e1, bv)));
    const float x1v1 = x1b * vvb;
    #pragma unroll
    for (int j = 0; j < kS; ++j) s[j] = fmaf(p[j], s[j], x1v1);
    m2 = a0; m1 = a1; n2 = e0; n1 = e1;
    xv[k] = __float22half2_rn(make_float2(x0, x1v1));
  }

  // publish chunk-end local state (from zero init)
  {
    float* Ad = A + (((size_t)b * kNC + ch) * kHid + d) * kS;
    #pragma unroll
    for (int j = 0; j < kS; ++j) Ad[j] = s[j];
  }

  // ---- device-scope software barrier (all 512 blocks co-resident) --------
  __syncthreads();   // block's A stores issued (vmcnt drained before barrier)
  if (tid == 0) {
    __hip_atomic_fetch_add(cnt, 1u, __ATOMIC_ACQ_REL, __HIP_MEMORY_SCOPE_AGENT);
    unsigned long guard = 0;
    while (__hip_atomic_load(cnt, __ATOMIC_ACQUIRE,
                             __HIP_MEMORY_SCOPE_AGENT) < kNBlk) {
      __builtin_amdgcn_s_sleep(2);
      if (++guard > (1ul << 27)) break;   // safety valve: never hang harness
    }
  }
  __syncthreads();

  // ---- combine: incoming state = scan over predecessor chunk states ------
  float si[kS];
  #pragma unroll
  for (int j = 0; j < kS; ++j) si[j] = 0.f;
  {
    float pC[kS];
    #pragma unroll
    for (int j = 0; j < kS; ++j) pC[j] = expf(lp[d*kS + j] * (float)kCL);
    for (int c = 0; c < ch; ++c) {      // <=31 iters; A is L3-resident (4 MB)
      const float* Ac = A + (((size_t)b * kNC + c) * kHid + d) * kS;
      const float4 q0 = *(const float4*)Ac;
      const float4 q1 = *(const float4*)(Ac + 4);
      si[0] = fmaf(pC[0], si[0], q0.x);
      si[1] = fmaf(pC[1], si[1], q0.y);
      si[2] = fmaf(pC[2], si[2], q0.z);
      si[3] = fmaf(pC[3], si[3], q0.w);
      si[4] = fmaf(pC[4], si[4], q1.x);
      si[5] = fmaf(pC[5], si[5], q1.y);
      si[6] = fmaf(pC[6], si[6], q1.z);
      si[7] = fmaf(pC[7], si[7], q1.w);
    }
  }

  // ---- phase B: x2 conv + scan from si + gated output --------------------
  const float w20 = w[c2*3+0], w21 = w[c2*3+1], w22 = w[c2*3+2], b2 = bias[c2];
  const float Dd = Dv[d];
  float rr[kS];
  #pragma unroll
  for (int j = 0; j < kS; ++j) rr[j] = res[d*kS + j];

  float g2 = 0.f, g1 = 0.f;
  if (l0 >= 2) g2 = ub[(size_t)(l0-2)*kC3 + c2];
  if (l0 >= 1) g1 = ub[(size_t)(l0-1)*kC3 + c2];

  float* ob = out + ((size_t)b * kL + l0) * kHid + d;

  #pragma unroll
  for (int k = 0; k < kPair; ++k) {
    const float z0 = up[(size_t)(2*k  )*kC3 + c2];
    const float z1 = up[(size_t)(2*k+1)*kC3 + c2];
    const float2 xf = __half22float2(xv[k]);
    const float x2a = fmaf(w20, g2, fmaf(w21, g1, fmaf(w22, z0, b2)));
    const float x2b = fmaf(w20, g1, fmaf(w21, z0, fmaf(w22, z1, b2)));
    #pragma unroll
    for (int j = 0; j < kS; ++j) si[j] = fmaf(p[j], si[j], xf.x);
    float y0 = 0.f;
    #pragma unroll
    for (int j = 0; j < kS; ++j) y0 = fmaf(rr[j], si[j], y0);
    ob[(size_t)(2*k) * kHid] = fmaf(xf.x, Dd, y0) * x2a;
    #pragma unroll
    for (int j = 0; j < kS; ++j) si[j] = fmaf(p[j], si[j], xf.y);
    float y1 = 0.f;
    #pragma unroll
    for (int j = 0; j < kS; ++j) y1 = fmaf(rr[j], si[j], y1);
    ob[(size_t)(2*k+1) * kHid] = fmaf(xf.y, Dd, y1) * x2b;
    g2 = z0; g1 = z1;
  }
}

extern "C" void kernel_launch(void* const* d_in, const int* in_sizes, int n_in,
                              void* d_out, int out_size, void* d_ws, size_t ws_size,
                              hipStream_t stream) {
  const float* u    = (const float*)d_in[0];  // [B, L, 3*HID] fp32
  const float* w    = (const float*)d_in[1];  // [3*HID, 1, 3]
  const float* bias = (const float*)d_in[2];  // [3*HID]
  const float* lp   = (const float*)d_in[3];  // [HID, S, 1]
  const float* res  = (const float*)d_in[4];  // [HID, S]
  const float* Dv   = (const float*)d_in[5];  // [HID]
  float* out = (float*)d_out;                 // [B, L, HID]
  float* A   = (float*)d_ws;                  // [B, NC, HID, S] = 4 MB
  unsigned* cnt = (unsigned*)((char*)d_ws + (size_t)kB * kNC * kHid * kS * 4);

  // workspace is poisoned each iteration -> zero the barrier counter
  hipMemsetAsync(cnt, 0, sizeof(unsigned), stream);
  hipLaunchKernelGGL(hyena_fused, dim3(kNBlk), dim3(256), 0, stream,
                     u, w, bias, lp, res, Dv, A, cnt, out);
}